// Round 12
// baseline (357.230 us; speedup 1.0000x reference)
//
#include <hip/hip_runtime.h>
#include <hip/hip_bf16.h>

#define N_   64
#define CIN  64
#define COUT 128
#define T_   300
#define V_   25
#define S_   3
#define NTV  (N_ * T_ * V_)       // 480000

#define TS     10
#define NTB    (T_ / TS)          // 30
#define NBLK   (N_ * NTB)         // 1920
#define RED_ROWS   64
#define RED_BLOCKS (NBLK / RED_ROWS)  // 30

// Z row stride: 512B data + 16B pad -> additive rotation swizzle for free
#define ROWB   528

// ws layout (float offsets), ~4.2 MB total
#define WS_P    0
#define WS_P2   (WS_P + NBLK * 512)          // 983040
#define WS_COEF (WS_P2 + RED_BLOCKS * 512)   // 998400
#define WS_WF   (WS_COEF + 512)              // 998912
#define WS_WSF  (WS_WF + 16384)              // 1015296
#define WS_AF   (WS_WSF + 16384)             // 1031680

typedef __attribute__((ext_vector_type(8))) short short8;
typedef __attribute__((ext_vector_type(4))) float f32x4;

// LDS-only barrier: drain LDS ops, leave global-load vmcnt in flight.
#define LDS_BARRIER() asm volatile("s_waitcnt lgkmcnt(0)\n\ts_barrier" ::: "memory")

__device__ __forceinline__ unsigned short bfbits(float f) {
    union { __hip_bfloat16 h; unsigned short u; } cv;
    cv.h = __float2bfloat16(f);
    return cv.u;
}
// packed RNE cvt: v_cvt_pk_bf16_f32 (low word = lo)
__device__ __forceinline__ unsigned int pack2(float lo, float hi) {
    union { __hip_bfloat162 h2; unsigned int u; } cv;
    cv.h2 = __float22bfloat162_rn(float2{lo, hi});
    return cv.u;
}

// ---------------------------------------------------------------------------
// Z tile layout: 32 rows (w) x 528B. Within a row, the 16B chunk holding
// k = ks*32 + lq*8 .. +7 lives at byte (lq*8 + ks)*16. Reads/writes are then
// base-register + compile-time immediate (no per-op address VALU), and the
// 528B stride rotates slot%32 by one per row:
//   read slot%32 = lr + 8*lq + ks  -> exactly 2-way lane aliasing (free).
// ---------------------------------------------------------------------------

// k_prep: Wf[((oh*2+of)*8+ks)*64+lane][8] = W_all[o=oh*32+of*16+(lane&15)][k=ks*32+(lane>>4)*8+j]
//   W_all[o][k] = k<192 ? W[k/64][o][k%64] : down_W[o][k-192]
// Af[((s*2+wf)*64+lane)*8+j]: s<3 -> A_adj[v][w] zero-padded; s==3 -> I[v][w]
__global__ __launch_bounds__(256) void k_prep(const float* __restrict__ W,
                                              const float* __restrict__ dW,
                                              const float* __restrict__ A,
                                              const float* __restrict__ alpha,
                                              unsigned short* __restrict__ Wf,
                                              unsigned short* __restrict__ Af) {
    int i = blockIdx.x * 256 + threadIdx.x;  // 32768
    {
        int j = i & 7, lane = (i >> 3) & 63, ks = (i >> 9) & 7;
        int of = (i >> 12) & 1, oh = i >> 13;
        int o = oh * 32 + of * 16 + (lane & 15);
        int k = ks * 32 + (lane >> 4) * 8 + j;
        float wv = (k < 192) ? W[(k >> 6) * (COUT * CIN) + o * CIN + (k & 63)]
                             : dW[o * CIN + (k - 192)];
        Wf[i] = bfbits(wv);
    }
    if (i < 4096) {
        int j = i & 7, lane = (i >> 3) & 63, wf = (i >> 9) & 1, s = i >> 10;
        int v = (lane >> 4) * 8 + j, w = wf * 16 + (lane & 15);
        float av;
        if (s < 3)
            av = (v < V_ && w < V_)
                   ? A[(s * V_ + v) * V_ + w] + ((v == w) ? alpha[0] : 0.f)
                   : 0.f;
        else
            av = (v == w && v < V_) ? 1.f : 0.f;
        Af[i] = bfbits(av);
    }
}

// k_prep2: Wf scaled: rows k<192 by ay[o], k>=192 by ar[o]
__global__ __launch_bounds__(256) void k_prep2(const float* __restrict__ W,
                                               const float* __restrict__ dW,
                                               const float* __restrict__ coef,
                                               unsigned short* __restrict__ Wsf) {
    int i = blockIdx.x * 256 + threadIdx.x;
    int j = i & 7, lane = (i >> 3) & 63, ks = (i >> 9) & 7;
    int of = (i >> 12) & 1, oh = i >> 13;
    int o = oh * 32 + of * 16 + (lane & 15);
    int k = ks * 32 + (lane >> 4) * 8 + j;
    float wv = (k < 192) ? W[(k >> 6) * (COUT * CIN) + o * CIN + (k & 63)]
                         : dW[o * CIN + (k - 192)];
    float sc = (k < 192) ? coef[o] : coef[COUT + o];
    Wsf[i] = bfbits(wv * sc);
}

// ---------------------------------------------------------------------------
// Raw (un-converted) x slot: loads for x[c=oh*16+lr][v], lane (lq,lr).
struct XRaw { f32x4 a0, a1; float s; };

__device__ __forceinline__ XRaw load_raw(const float* __restrict__ base, int lq) {
    XRaw r;
    if (lq < 3) {
        r.a0 = *(const f32x4*)(base + lq * 8);
        r.a1 = *(const f32x4*)(base + lq * 8 + 4);
        r.s = 0.f;
    } else {
        r.s = base[24];
        r.a0 = (f32x4){0.f, 0.f, 0.f, 0.f};
        r.a1 = (f32x4){0.f, 0.f, 0.f, 0.f};
    }
    return r;
}

__device__ __forceinline__ short8 cvt_xfr(const XRaw& x, int lq) {
    union { short8 s8; unsigned int u[4]; } b;
    if (lq < 3) {
        b.u[0] = pack2(x.a0[0], x.a0[1]);
        b.u[1] = pack2(x.a0[2], x.a0[3]);
        b.u[2] = pack2(x.a1[0], x.a1[1]);
        b.u[3] = pack2(x.a1[2], x.a1[3]);
    } else {
        b.u[0] = pack2(x.s, 0.f);
        b.u[1] = 0; b.u[2] = 0; b.u[3] = 0;
    }
    return b.s8;
}

// Staging: 8 MFMA (subsets 0..2 + identity, wf=0..1) for c-quarter cq = oh.
// A-frags streamed from global (L1-hot 6KB table). Lane holds D rows
// c = cq*16 + lq*4 + r at col w = wf*16 + lr; ds_write_b64 at
// base_wr + (wf*16*ROWB + s*32) with base_wr precomputed (additive layout).
__device__ __forceinline__ void stage(char* zwr, const unsigned short* __restrict__ Af,
                                      short8 xfr, int lane) {
    const f32x4 zero = {0.f, 0.f, 0.f, 0.f};
#pragma unroll
    for (int s = 0; s < 4; ++s)
#pragma unroll
        for (int wf = 0; wf < 2; ++wf) {
            short8 af = *(const short8*)(Af + ((s * 2 + wf) * 64 + lane) * 8);
            f32x4 d = __builtin_amdgcn_mfma_f32_16x16x32_bf16(xfr, af, zero, 0, 0, 0);
            unsigned long long pk = (unsigned long long)pack2(d[0], d[1])
                                  | ((unsigned long long)pack2(d[2], d[3]) << 32);
            *(unsigned long long*)(zwr + (wf * 16 * ROWB + s * 32)) = pk;
        }
}

// ---------------------------------------------------------------------------
// Main kernel: 256 threads = 4 waves; wave oh owns o in [oh*32, oh*32+32)
// (wfr = 64 regs) and stages c-quarter cq = oh. Z = [w(32) x k(256)]:
// k<192 = XA, k>=192 = x (identity subset). One prefetch slot; LDS-only
// barriers; all ds addressing is base + immediate. STATS pass computes res
// (ks 6,7) first, drains, then reuses acc for y (ks 0..5) -> no accr regs.
template<bool STATS>
__global__ __launch_bounds__(256, 4) void k_gemm(
    const float* __restrict__ x, const unsigned short* __restrict__ Wf,
    const unsigned short* __restrict__ Af, const float* __restrict__ coef,
    float* __restrict__ P, float* __restrict__ out)
{
    __shared__ __align__(16) char Zt[2][32 * ROWB];   // 2 x 16.5 KB

    const int tid = threadIdx.x;
    const int oh = tid >> 6, lane = tid & 63;
    const int lq = lane >> 4, lr = lane & 15;

    const int bid = blockIdx.x;
    const int n = bid / NTB, tb = bid % NTB;
    const int t0 = tb * TS;

    // W fragments (64 regs)
    short8 wfr[2][8];
#pragma unroll
    for (int of = 0; of < 2; ++of)
#pragma unroll
        for (int ks = 0; ks < 8; ++ks)
            wfr[of][ks] = *(const short8*)(Wf + (((oh * 2 + of) * 8 + ks) * 64 + lane) * 8);

    float c0v[2] = {0.f, 0.f};
    if (!STATS) {
        c0v[0] = coef[2 * COUT + oh * 32 + lr];
        c0v[1] = coef[2 * COUT + oh * 32 + 16 + lr];
    }

    float sy[2] = {0.f, 0.f}, sy2[2] = {0.f, 0.f};
    float sr[2] = {0.f, 0.f}, sr2[2] = {0.f, 0.f};

    const int c = oh * 16 + lr;
    const float* xrow = x + ((size_t)(n * CIN + c) * T_) * V_;

    // per-lane LDS base offsets (computed once; all ds ops use +immediate)
    const int base_rd = lr * ROWB + lq * 128;                         // reads
    const int base_wr = lr * ROWB + (oh & 1) * 256 + (lq >> 1) * 128
                      + (lq & 1) * 8 + (oh >> 1) * 16;                // writes

    // Prologue: stage t0 into buf0; issue t0+1 load into the slot.
    {
        XRaw r0 = load_raw(xrow + (size_t)t0 * V_, lq);
        stage((char*)Zt[0] + base_wr, Af, cvt_xfr(r0, lq), lane);
    }
    XRaw slotA = load_raw(xrow + (size_t)(t0 + 1) * V_, lq);

    const f32x4 zero = {0.f, 0.f, 0.f, 0.f};

    for (int tt = 0; tt < TS; ++tt) {
        const int t = t0 + tt;
        const char* zb = (const char*)Zt[tt & 1] + base_rd;
        LDS_BARRIER();

        f32x4 acc[2][2];   // [mf][of]

        if constexpr (STATS) {
            // ---- res: ks 6,7 ----
#pragma unroll
            for (int ks = 6; ks < 8; ++ks) {
                short8 za[2];
                za[0] = *(const short8*)(zb + ks * 16);
                za[1] = *(const short8*)(zb + 16 * ROWB + ks * 16);
#pragma unroll
                for (int mf = 0; mf < 2; ++mf)
#pragma unroll
                    for (int of = 0; of < 2; ++of)
                        acc[mf][of] = __builtin_amdgcn_mfma_f32_16x16x32_bf16(
                            za[mf], wfr[of][ks], ks == 6 ? zero : acc[mf][of], 0, 0, 0);
            }
#pragma unroll
            for (int of = 0; of < 2; ++of)
#pragma unroll
                for (int mf = 0; mf < 2; ++mf)
#pragma unroll
                    for (int r = 0; r < 4; ++r) {
                        float rv = acc[mf][of][r];
                        sr[of] += rv; sr2[of] = fmaf(rv, rv, sr2[of]);
                    }
            // ---- y: ks 0..5 (reuse acc) ----
#pragma unroll
            for (int ks = 0; ks < 6; ++ks) {
                short8 za[2];
                za[0] = *(const short8*)(zb + ks * 16);
                za[1] = *(const short8*)(zb + 16 * ROWB + ks * 16);
#pragma unroll
                for (int mf = 0; mf < 2; ++mf)
#pragma unroll
                    for (int of = 0; of < 2; ++of)
                        acc[mf][of] = __builtin_amdgcn_mfma_f32_16x16x32_bf16(
                            za[mf], wfr[of][ks], ks == 0 ? zero : acc[mf][of], 0, 0, 0);
            }
            // stage t+1 (independent of y-drain below)
            if (tt + 1 < TS)
                stage((char*)Zt[(tt + 1) & 1] + base_wr, Af, cvt_xfr(slotA, lq), lane);
            if (tt + 2 < TS)
                slotA = load_raw(xrow + (size_t)(t + 2) * V_, lq);
#pragma unroll
            for (int of = 0; of < 2; ++of)
#pragma unroll
                for (int mf = 0; mf < 2; ++mf)
#pragma unroll
                    for (int r = 0; r < 4; ++r) {
                        float yv = acc[mf][of][r];
                        sy[of] += yv; sy2[of] = fmaf(yv, yv, sy2[of]);
                    }
        } else {
#pragma unroll
            for (int ks = 0; ks < 8; ++ks) {
                short8 za[2];
                za[0] = *(const short8*)(zb + ks * 16);
                za[1] = *(const short8*)(zb + 16 * ROWB + ks * 16);
#pragma unroll
                for (int mf = 0; mf < 2; ++mf)
#pragma unroll
                    for (int of = 0; of < 2; ++of)
                        acc[mf][of] = __builtin_amdgcn_mfma_f32_16x16x32_bf16(
                            za[mf], wfr[of][ks], ks == 0 ? zero : acc[mf][of], 0, 0, 0);
            }
            // stage t+1, then issue t+2's load
            if (tt + 1 < TS)
                stage((char*)Zt[(tt + 1) & 1] + base_wr, Af, cvt_xfr(slotA, lq), lane);
            if (tt + 2 < TS)
                slotA = load_raw(xrow + (size_t)(t + 2) * V_, lq);

#pragma unroll
            for (int of = 0; of < 2; ++of) {
                int o = oh * 32 + of * 16 + lr;
                float* rowp = out + ((size_t)(n * COUT + o) * T_ + t) * V_;
                f32x4 v0;
#pragma unroll
                for (int r = 0; r < 4; ++r) v0[r] = fmaxf(acc[0][of][r] + c0v[of], 0.f);
                *(f32x4*)(rowp + lq * 4) = v0;           // w = lq*4 .. lq*4+3
                if (lq < 2) {
                    f32x4 v1;
#pragma unroll
                    for (int r = 0; r < 4; ++r) v1[r] = fmaxf(acc[1][of][r] + c0v[of], 0.f);
                    *(f32x4*)(rowp + 16 + lq * 4) = v1;  // w = 16..23
                } else if (lq == 2) {
                    rowp[24] = fmaxf(acc[1][of][0] + c0v[of], 0.f);  // w = 24
                }
            }
        }
    }

    if constexpr (STATS) {
#pragma unroll
        for (int of = 0; of < 2; ++of) {
            sy[of]  += __shfl_xor(sy[of], 16);  sy[of]  += __shfl_xor(sy[of], 32);
            sy2[of] += __shfl_xor(sy2[of], 16); sy2[of] += __shfl_xor(sy2[of], 32);
            sr[of]  += __shfl_xor(sr[of], 16);  sr[of]  += __shfl_xor(sr[of], 32);
            sr2[of] += __shfl_xor(sr2[of], 16); sr2[of] += __shfl_xor(sr2[of], 32);
        }
        if (lq == 0) {
            float* p = P + (size_t)bid * 512;
#pragma unroll
            for (int of = 0; of < 2; ++of) {
                int o = oh * 32 + of * 16 + lr;
                p[o] = sy[of]; p[128 + o] = sy2[of];
                p[256 + o] = sr[of]; p[384 + o] = sr2[of];
            }
        }
    }
}

// ---------------------------------------------------------------------------
__global__ __launch_bounds__(256) void k_red(const float* __restrict__ P,
                                             float* __restrict__ P2) {
    const int tid = threadIdx.x;
    float a0 = 0.f, a1 = 0.f;
    const int row0 = blockIdx.x * RED_ROWS;
    for (int r = 0; r < RED_ROWS; ++r) {
        const float* p = P + (size_t)(row0 + r) * 512;
        a0 += p[tid];
        a1 += p[256 + tid];
    }
    P2[blockIdx.x * 512 + tid] = a0;
    P2[blockIdx.x * 512 + 256 + tid] = a1;
}

__global__ __launch_bounds__(128) void k_coef(
    const float* __restrict__ P2, const float* __restrict__ gamma,
    const float* __restrict__ beta, const float* __restrict__ dgamma,
    const float* __restrict__ dbeta, const float* __restrict__ b,
    const float* __restrict__ db, float* __restrict__ coef) {
    const int o = threadIdx.x;
    float sy = 0.f, sy2 = 0.f, sr = 0.f, sr2 = 0.f;
    for (int r2 = 0; r2 < RED_BLOCKS; ++r2) {
        const float* p = P2 + r2 * 512;
        sy += p[o]; sy2 += p[128 + o]; sr += p[256 + o]; sr2 += p[384 + o];
    }
    const float bsum = b[o] + b[COUT + o] + b[2 * COUT + o];
    const float dbo = db[o];
    float syb  = sy + (float)NTV * bsum;
    float sy2b = sy2 + 2.f * bsum * sy + (float)NTV * bsum * bsum;
    float srb  = sr + (float)NTV * dbo;
    float sr2b = sr2 + 2.f * dbo * sr + (float)NTV * dbo * dbo;
    const float invn = 1.f / (float)NTV;
    float my = syb * invn, mr = srb * invn;
    float vy = fmaf(-my, my, sy2b * invn);
    float vr = fmaf(-mr, mr, sr2b * invn);
    float ay = rsqrtf(vy + 1e-5f) * gamma[o];
    float ar = rsqrtf(vr + 1e-5f) * dgamma[o];
    float c0 = beta[o] - my * ay + dbeta[o] - mr * ar + ay * bsum + ar * dbo;
    coef[o] = ay; coef[COUT + o] = ar; coef[2 * COUT + o] = c0;
}

// ---------------------------------------------------------------------------
extern "C" void kernel_launch(void* const* d_in, const int* in_sizes, int n_in,
                              void* d_out, int out_size, void* d_ws, size_t ws_size,
                              hipStream_t stream) {
    const float* x      = (const float*)d_in[0];
    const float* A      = (const float*)d_in[1];
    const float* W      = (const float*)d_in[2];
    const float* b      = (const float*)d_in[3];
    const float* alpha  = (const float*)d_in[4];
    const float* gamma  = (const float*)d_in[5];
    const float* beta   = (const float*)d_in[6];
    const float* dW     = (const float*)d_in[7];
    const float* db     = (const float*)d_in[8];
    const float* dgamma = (const float*)d_in[9];
    const float* dbeta  = (const float*)d_in[10];

    float* ws   = (float*)d_ws;
    float* P    = ws + WS_P;
    float* P2   = ws + WS_P2;
    float* coef = ws + WS_COEF;
    unsigned short* Wf  = (unsigned short*)(ws + WS_WF);
    unsigned short* Wsf = (unsigned short*)(ws + WS_WSF);
    unsigned short* Af  = (unsigned short*)(ws + WS_AF);
    float* out  = (float*)d_out;

    k_prep<<<128, 256, 0, stream>>>(W, dW, A, alpha, Wf, Af);
    k_gemm<true><<<NBLK, 256, 0, stream>>>(x, Wf, Af, nullptr, P, nullptr);
    k_red<<<RED_BLOCKS, 256, 0, stream>>>(P, P2);
    k_coef<<<1, 128, 0, stream>>>(P2, gamma, beta, dgamma, dbeta, b, db, coef);
    k_prep2<<<128, 256, 0, stream>>>(W, dW, coef, Wsf);
    k_gemm<false><<<NBLK, 256, 0, stream>>>(x, Wsf, Af, coef, nullptr, out);
}

// Round 13
// 221.548 us; speedup vs baseline: 1.6124x; 1.6124x over previous
//
#include <hip/hip_runtime.h>
#include <hip/hip_bf16.h>

#define N_   64
#define CIN  64
#define COUT 128
#define T_   300
#define V_   25
#define S_   3
#define NTV  (N_ * T_ * V_)       // 480000

#define TS     10
#define NTB    (T_ / TS)          // 30
#define NBLK   (N_ * NTB)         // 1920
#define RED_ROWS   64
#define RED_BLOCKS (NBLK / RED_ROWS)  // 30

// ws layout (float offsets), ~4.2 MB total
#define WS_P    0
#define WS_P2   (WS_P + NBLK * 512)          // 983040
#define WS_COEF (WS_P2 + RED_BLOCKS * 512)   // 998400
#define WS_WF   (WS_COEF + 512)              // 998912
#define WS_WSF  (WS_WF + 16384)              // 1015296
#define WS_AF   (WS_WSF + 16384)             // 1031680

typedef __attribute__((ext_vector_type(8))) short short8;
typedef __attribute__((ext_vector_type(4))) float f32x4;

// LDS-only barrier: drain LDS ops, leave global-load vmcnt in flight.
#define LDS_BARRIER() asm volatile("s_waitcnt lgkmcnt(0)\n\ts_barrier" ::: "memory")

__device__ __forceinline__ unsigned short bfbits(float f) {
    union { __hip_bfloat16 h; unsigned short u; } cv;
    cv.h = __float2bfloat16(f);
    return cv.u;
}
__device__ __forceinline__ unsigned int pack2(float lo, float hi) {
    union { __hip_bfloat162 h2; unsigned int u; } cv;
    cv.h2 = __float22bfloat162_rn(float2{lo, hi});
    return cv.u;
}

// Z tile: 32 rows (w) x 256 bf16 cols (k), 512 B rows, full-row XOR swizzle.
__device__ __forceinline__ int zoff(int nl, int k) {
    int slot = (k >> 3) ^ (nl & 31);
    return nl * 512 + slot * 16 + (k & 7) * 2;
}

// ---------------------------------------------------------------------------
// k_prep: Wf[((oh*2+of)*8+ks)*64+lane][8] = W_all[o=oh*32+of*16+(lane&15)][k=ks*32+(lane>>4)*8+j]
//   W_all[o][k] = k<192 ? W[k/64][o][k%64] : down_W[o][k-192]
// Af[((s*2+wf)*64+lane)*8+j]: s<3 -> A_adj[v][w] zero-padded; s==3 -> I[v][w]
__global__ __launch_bounds__(256) void k_prep(const float* __restrict__ W,
                                              const float* __restrict__ dW,
                                              const float* __restrict__ A,
                                              const float* __restrict__ alpha,
                                              unsigned short* __restrict__ Wf,
                                              unsigned short* __restrict__ Af) {
    int i = blockIdx.x * 256 + threadIdx.x;  // 32768
    {
        int j = i & 7, lane = (i >> 3) & 63, ks = (i >> 9) & 7;
        int of = (i >> 12) & 1, oh = i >> 13;
        int o = oh * 32 + of * 16 + (lane & 15);
        int k = ks * 32 + (lane >> 4) * 8 + j;
        float wv = (k < 192) ? W[(k >> 6) * (COUT * CIN) + o * CIN + (k & 63)]
                             : dW[o * CIN + (k - 192)];
        Wf[i] = bfbits(wv);
    }
    if (i < 4096) {
        int j = i & 7, lane = (i >> 3) & 63, wf = (i >> 9) & 1, s = i >> 10;
        int v = (lane >> 4) * 8 + j, w = wf * 16 + (lane & 15);
        float av;
        if (s < 3)
            av = (v < V_ && w < V_)
                   ? A[(s * V_ + v) * V_ + w] + ((v == w) ? alpha[0] : 0.f)
                   : 0.f;
        else
            av = (v == w && v < V_) ? 1.f : 0.f;
        Af[i] = bfbits(av);
    }
}

// k_prep2: Wf scaled: rows k<192 by ay[o], k>=192 by ar[o]
__global__ __launch_bounds__(256) void k_prep2(const float* __restrict__ W,
                                               const float* __restrict__ dW,
                                               const float* __restrict__ coef,
                                               unsigned short* __restrict__ Wsf) {
    int i = blockIdx.x * 256 + threadIdx.x;
    int j = i & 7, lane = (i >> 3) & 63, ks = (i >> 9) & 7;
    int of = (i >> 12) & 1, oh = i >> 13;
    int o = oh * 32 + of * 16 + (lane & 15);
    int k = ks * 32 + (lane >> 4) * 8 + j;
    float wv = (k < 192) ? W[(k >> 6) * (COUT * CIN) + o * CIN + (k & 63)]
                         : dW[o * CIN + (k - 192)];
    float sc = (k < 192) ? coef[o] : coef[COUT + o];
    Wsf[i] = bfbits(wv * sc);
}

// ---------------------------------------------------------------------------
// Raw (un-converted) x slot: loads for x[c=oh*16+lr][v], lane (lq,lr).
struct XRaw { f32x4 a0, a1; float s; };

__device__ __forceinline__ XRaw load_raw(const float* __restrict__ base, int lq) {
    XRaw r;
    if (lq < 3) {
        r.a0 = *(const f32x4*)(base + lq * 8);
        r.a1 = *(const f32x4*)(base + lq * 8 + 4);
        r.s = 0.f;
    } else {
        r.s = base[24];
        r.a0 = (f32x4){0.f, 0.f, 0.f, 0.f};
        r.a1 = (f32x4){0.f, 0.f, 0.f, 0.f};
    }
    return r;
}

__device__ __forceinline__ short8 cvt_xfr(const XRaw& x, int lq) {
    union { short8 s8; unsigned int u[4]; } b;
    if (lq < 3) {
        b.u[0] = pack2(x.a0[0], x.a0[1]);
        b.u[1] = pack2(x.a0[2], x.a0[3]);
        b.u[2] = pack2(x.a1[0], x.a1[1]);
        b.u[3] = pack2(x.a1[2], x.a1[3]);
    } else {
        b.u[0] = pack2(x.s, 0.f);
        b.u[1] = 0; b.u[2] = 0; b.u[3] = 0;
    }
    return b.s8;
}

// Staging: 8 MFMA (subsets 0..2 + identity, wf=0..1), A-frags from LDS,
// packed ds_write_b64. Lane holds D rows c=oh*16+lq*4+r at col w=wf*16+lr.
__device__ __forceinline__ void stage(char* zb, const unsigned short* Alds,
                                      short8 xfr, int oh, int lq, int lr, int lane) {
    const f32x4 zero = {0.f, 0.f, 0.f, 0.f};
#pragma unroll
    for (int s = 0; s < 4; ++s)
#pragma unroll
        for (int wf = 0; wf < 2; ++wf) {
            short8 af = *(const short8*)(Alds + ((s * 2 + wf) * 64 + lane) * 8);
            f32x4 d = __builtin_amdgcn_mfma_f32_16x16x32_bf16(xfr, af, zero, 0, 0, 0);
            unsigned long long pk = (unsigned long long)pack2(d[0], d[1])
                                  | ((unsigned long long)pack2(d[2], d[3]) << 32);
            int row = wf * 16 + lr;
            int k = s * 64 + oh * 16 + lq * 4;
            *(unsigned long long*)(zb + zoff(row, k)) = pk;
        }
}

// ---------------------------------------------------------------------------
// Main kernel: 256 threads = 4 waves; wave oh owns o in [oh*32, oh*32+32).
// Per t-step: Z = [w(32) x k(256)]: k<192 = XA, k>=192 = x (identity subset).
// Prefetch depth 2; LDS-only barriers. Blocks are XCD-chunk-swizzled so the
// 30 blocks sharing one x[n] slab run on the same XCD (L2 locality).
// STATS: res (ks 6,7) computed first and drained, acc regs reused for y.
template<bool STATS>
__global__ __launch_bounds__(256, 3) void k_gemm(
    const float* __restrict__ x, const unsigned short* __restrict__ Wf,
    const unsigned short* __restrict__ Af, const float* __restrict__ coef,
    float* __restrict__ P, float* __restrict__ out)
{
    __shared__ __align__(16) unsigned short Zt[2][32 * 256];   // 32 KB dbuf
    __shared__ __align__(16) unsigned short Alds[8 * 64 * 8];  // 8 KB

    const int tid = threadIdx.x;
    const int oh = tid >> 6, lane = tid & 63;
    const int lq = lane >> 4, lr = lane & 15;

    // bijective XCD chunked swizzle (NBLK % 8 == 0)
    const int bid0 = blockIdx.x;
    const int bid = (bid0 & 7) * (NBLK / 8) + (bid0 >> 3);
    const int n = bid / NTB, tb = bid % NTB;
    const int t0 = tb * TS;

    for (int i = tid; i < 512; i += 256)
        *(short8*)(Alds + i * 8) = *(const short8*)(Af + i * 8);

    // W fragments (64 regs) — the only large register-resident table
    short8 wfr[2][8];
#pragma unroll
    for (int of = 0; of < 2; ++of)
#pragma unroll
        for (int ks = 0; ks < 8; ++ks)
            wfr[of][ks] = *(const short8*)(Wf + (((oh * 2 + of) * 8 + ks) * 64 + lane) * 8);

    float c0v[2] = {0.f, 0.f};
    if (!STATS) {
        c0v[0] = coef[2 * COUT + oh * 32 + lr];
        c0v[1] = coef[2 * COUT + oh * 32 + 16 + lr];
    }

    float sy[2] = {0.f, 0.f}, sy2[2] = {0.f, 0.f};
    float sr[2] = {0.f, 0.f}, sr2[2] = {0.f, 0.f};

    const int c = oh * 16 + lr;
    const float* xrow = x + ((size_t)(n * CIN + c) * T_) * V_;

    LDS_BARRIER();  // Alds ready

    // Prologue: stage t0 into buf0; issue t0+1 load into slot A.
    {
        XRaw r0 = load_raw(xrow + (size_t)t0 * V_, lq);
        stage((char*)Zt[0], Alds, cvt_xfr(r0, lq), oh, lq, lr, lane);
    }
    XRaw slotA = load_raw(xrow + (size_t)(t0 + 1) * V_, lq);

    const f32x4 zero = {0.f, 0.f, 0.f, 0.f};

    for (int tt = 0; tt < TS; ++tt) {
        const int t = t0 + tt;
        char* zb = (char*)Zt[tt & 1];
        LDS_BARRIER();

        // issue t+2's x load (survives barriers)
        XRaw slotB;
        if (tt + 2 < TS) slotB = load_raw(xrow + (size_t)(t + 2) * V_, lq);
        else { slotB.a0 = zero; slotB.a1 = zero; slotB.s = 0.f; }

        // stage t+1 from slot A (writes the other buffer)
        if (tt + 1 < TS)
            stage((char*)Zt[(tt + 1) & 1], Alds, cvt_xfr(slotA, lq), oh, lq, lr, lane);

        f32x4 acc[2][2];   // [mf][of]

        if constexpr (STATS) {
            // ---- res: ks 6,7 ----
#pragma unroll
            for (int ks = 6; ks < 8; ++ks) {
                short8 za[2];
                za[0] = *(const short8*)(zb + zoff(lr, ks * 32 + lq * 8));
                za[1] = *(const short8*)(zb + zoff(16 + lr, ks * 32 + lq * 8));
#pragma unroll
                for (int mf = 0; mf < 2; ++mf)
#pragma unroll
                    for (int of = 0; of < 2; ++of)
                        acc[mf][of] = __builtin_amdgcn_mfma_f32_16x16x32_bf16(
                            za[mf], wfr[of][ks], ks == 6 ? zero : acc[mf][of], 0, 0, 0);
            }
#pragma unroll
            for (int of = 0; of < 2; ++of)
#pragma unroll
                for (int mf = 0; mf < 2; ++mf)
#pragma unroll
                    for (int r = 0; r < 4; ++r) {
                        float rv = acc[mf][of][r];
                        sr[of] += rv; sr2[of] = fmaf(rv, rv, sr2[of]);
                    }
            // ---- y: ks 0..5 (reuse acc regs) ----
#pragma unroll
            for (int ks = 0; ks < 6; ++ks) {
                short8 za[2];
                za[0] = *(const short8*)(zb + zoff(lr, ks * 32 + lq * 8));
                za[1] = *(const short8*)(zb + zoff(16 + lr, ks * 32 + lq * 8));
#pragma unroll
                for (int mf = 0; mf < 2; ++mf)
#pragma unroll
                    for (int of = 0; of < 2; ++of)
                        acc[mf][of] = __builtin_amdgcn_mfma_f32_16x16x32_bf16(
                            za[mf], wfr[of][ks], ks == 0 ? zero : acc[mf][of], 0, 0, 0);
            }
#pragma unroll
            for (int of = 0; of < 2; ++of)
#pragma unroll
                for (int mf = 0; mf < 2; ++mf)
#pragma unroll
                    for (int r = 0; r < 4; ++r) {
                        float yv = acc[mf][of][r];
                        sy[of] += yv; sy2[of] = fmaf(yv, yv, sy2[of]);
                    }
        } else {
#pragma unroll
            for (int ks = 0; ks < 8; ++ks) {
                short8 za[2];
                za[0] = *(const short8*)(zb + zoff(lr, ks * 32 + lq * 8));
                za[1] = *(const short8*)(zb + zoff(16 + lr, ks * 32 + lq * 8));
#pragma unroll
                for (int mf = 0; mf < 2; ++mf)
#pragma unroll
                    for (int of = 0; of < 2; ++of)
                        acc[mf][of] = __builtin_amdgcn_mfma_f32_16x16x32_bf16(
                            za[mf], wfr[of][ks], ks == 0 ? zero : acc[mf][of], 0, 0, 0);
            }
#pragma unroll
            for (int of = 0; of < 2; ++of) {
                int o = oh * 32 + of * 16 + lr;
                float* rowp = out + ((size_t)(n * COUT + o) * T_ + t) * V_;
                f32x4 v0;
#pragma unroll
                for (int r = 0; r < 4; ++r) v0[r] = fmaxf(acc[0][of][r] + c0v[of], 0.f);
                *(f32x4*)(rowp + lq * 4) = v0;           // w = lq*4 .. lq*4+3
                if (lq < 2) {
                    f32x4 v1;
#pragma unroll
                    for (int r = 0; r < 4; ++r) v1[r] = fmaxf(acc[1][of][r] + c0v[of], 0.f);
                    *(f32x4*)(rowp + 16 + lq * 4) = v1;  // w = 16..23
                } else if (lq == 2) {
                    rowp[24] = fmaxf(acc[1][of][0] + c0v[of], 0.f);  // w = 24
                }
            }
        }

        // rotate prefetch slots (statically indexed register moves)
        slotA.a0 = slotB.a0; slotA.a1 = slotB.a1; slotA.s = slotB.s;
    }

    if constexpr (STATS) {
#pragma unroll
        for (int of = 0; of < 2; ++of) {
            sy[of]  += __shfl_xor(sy[of], 16);  sy[of]  += __shfl_xor(sy[of], 32);
            sy2[of] += __shfl_xor(sy2[of], 16); sy2[of] += __shfl_xor(sy2[of], 32);
            sr[of]  += __shfl_xor(sr[of], 16);  sr[of]  += __shfl_xor(sr[of], 32);
            sr2[of] += __shfl_xor(sr2[of], 16); sr2[of] += __shfl_xor(sr2[of], 32);
        }
        if (lq == 0) {
            float* p = P + (size_t)bid * 512;
#pragma unroll
            for (int of = 0; of < 2; ++of) {
                int o = oh * 32 + of * 16 + lr;
                p[o] = sy[of]; p[128 + o] = sy2[of];
                p[256 + o] = sr[of]; p[384 + o] = sr2[of];
            }
        }
    }
}

// ---------------------------------------------------------------------------
__global__ __launch_bounds__(256) void k_red(const float* __restrict__ P,
                                             float* __restrict__ P2) {
    const int tid = threadIdx.x;
    float a0 = 0.f, a1 = 0.f;
    const int row0 = blockIdx.x * RED_ROWS;
    for (int r = 0; r < RED_ROWS; ++r) {
        const float* p = P + (size_t)(row0 + r) * 512;
        a0 += p[tid];
        a1 += p[256 + tid];
    }
    P2[blockIdx.x * 512 + tid] = a0;
    P2[blockIdx.x * 512 + 256 + tid] = a1;
}

__global__ __launch_bounds__(128) void k_coef(
    const float* __restrict__ P2, const float* __restrict__ gamma,
    const float* __restrict__ beta, const float* __restrict__ dgamma,
    const float* __restrict__ dbeta, const float* __restrict__ b,
    const float* __restrict__ db, float* __restrict__ coef) {
    const int o = threadIdx.x;
    float sy = 0.f, sy2 = 0.f, sr = 0.f, sr2 = 0.f;
    for (int r2 = 0; r2 < RED_BLOCKS; ++r2) {
        const float* p = P2 + r2 * 512;
        sy += p[o]; sy2 += p[128 + o]; sr += p[256 + o]; sr2 += p[384 + o];
    }
    const float bsum = b[o] + b[COUT + o] + b[2 * COUT + o];
    const float dbo = db[o];
    float syb  = sy + (float)NTV * bsum;
    float sy2b = sy2 + 2.f * bsum * sy + (float)NTV * bsum * bsum;
    float srb  = sr + (float)NTV * dbo;
    float sr2b = sr2 + 2.f * dbo * sr + (float)NTV * dbo * dbo;
    const float invn = 1.f / (float)NTV;
    float my = syb * invn, mr = srb * invn;
    float vy = fmaf(-my, my, sy2b * invn);
    float vr = fmaf(-mr, mr, sr2b * invn);
    float ay = rsqrtf(vy + 1e-5f) * gamma[o];
    float ar = rsqrtf(vr + 1e-5f) * dgamma[o];
    float c0 = beta[o] - my * ay + dbeta[o] - mr * ar + ay * bsum + ar * dbo;
    coef[o] = ay; coef[COUT + o] = ar; coef[2 * COUT + o] = c0;
}

// ---------------------------------------------------------------------------
extern "C" void kernel_launch(void* const* d_in, const int* in_sizes, int n_in,
                              void* d_out, int out_size, void* d_ws, size_t ws_size,
                              hipStream_t stream) {
    const float* x      = (const float*)d_in[0];
    const float* A      = (const float*)d_in[1];
    const float* W      = (const float*)d_in[2];
    const float* b      = (const float*)d_in[3];
    const float* alpha  = (const float*)d_in[4];
    const float* gamma  = (const float*)d_in[5];
    const float* beta   = (const float*)d_in[6];
    const float* dW     = (const float*)d_in[7];
    const float* db     = (const float*)d_in[8];
    const float* dgamma = (const float*)d_in[9];
    const float* dbeta  = (const float*)d_in[10];

    float* ws   = (float*)d_ws;
    float* P    = ws + WS_P;
    float* P2   = ws + WS_P2;
    float* coef = ws + WS_COEF;
    unsigned short* Wf  = (unsigned short*)(ws + WS_WF);
    unsigned short* Wsf = (unsigned short*)(ws + WS_WSF);
    unsigned short* Af  = (unsigned short*)(ws + WS_AF);
    float* out  = (float*)d_out;

    k_prep<<<128, 256, 0, stream>>>(W, dW, A, alpha, Wf, Af);
    k_gemm<true><<<NBLK, 256, 0, stream>>>(x, Wf, Af, nullptr, P, nullptr);
    k_red<<<RED_BLOCKS, 256, 0, stream>>>(P, P2);
    k_coef<<<1, 128, 0, stream>>>(P2, gamma, beta, dgamma, dbeta, b, db, coef);
    k_prep2<<<128, 256, 0, stream>>>(W, dW, coef, Wsf);
    k_gemm<false><<<NBLK, 256, 0, stream>>>(x, Wsf, Af, coef, nullptr, out);
}